// Round 7
// baseline (477.976 us; speedup 1.0000x reference)
//
#include <hip/hip_runtime.h>
#include <math.h>

// Problem constants
#define T_SEQ 2048
#define CDIM  1024
#define NH    16
#define DHD   64
#define BATCH 4
#define MROWS (BATCH * T_SEQ)   // 8192
#define BHN   (BATCH * NH)      // 64

typedef _Float16 f16;
typedef __attribute__((ext_vector_type(8))) _Float16 f16x8;
typedef __attribute__((ext_vector_type(4))) _Float16 f16x4;
typedef __attribute__((ext_vector_type(4))) float f32x4;

// async global->LDS, 16B per lane; LDS dest = wave-uniform base + lane*16
__device__ __forceinline__ void gl_lds16(const f16* g, f16* l) {
    __builtin_amdgcn_global_load_lds(
        (const __attribute__((address_space(1))) void*)(g),
        (__attribute__((address_space(3))) void*)(l),
        16, 0, 0);
}

// ---------------------------------------------------------------------------
// RoPE trig tables (fp64 math)
// ---------------------------------------------------------------------------
__global__ void rope_tables_kernel(float* __restrict__ ctab, float* __restrict__ stab)
{
    int idx = blockIdx.x * 256 + threadIdx.x;   // 0 .. 2048*32-1
    int t = idx >> 5, i = idx & 31;
    double inv = pow(10000.0, -(double)(2 * i) / 64.0);
    double a = (double)t * inv;
    ctab[idx] = (float)cos(a);
    stab[idx] = (float)sin(a);
}

// ---------------------------------------------------------------------------
// X convert: fp32 [8192][1024] -> f16, same layout. 8 elems/thread.
// ---------------------------------------------------------------------------
__global__ __launch_bounds__(256) void xcvt_kernel(
    const float* __restrict__ X, f16* __restrict__ Xf)
{
    int idx = blockIdx.x * 256 + threadIdx.x;   // 8-elem chunk index
    const float4* src = (const float4*)X + (size_t)idx * 2;
    float4 a = src[0], b = src[1];
    f16x8 o;
    o[0] = (f16)a.x; o[1] = (f16)a.y; o[2] = (f16)a.z; o[3] = (f16)a.w;
    o[4] = (f16)b.x; o[5] = (f16)b.y; o[6] = (f16)b.z; o[7] = (f16)b.w;
    *((f16x8*)Xf + idx) = o;
}

// ---------------------------------------------------------------------------
// W transpose+convert: W [K][N] fp32 -> Wt [N][K] f16 (K=1024)
// ---------------------------------------------------------------------------
__global__ __launch_bounds__(64) void wcvt_kernel(
    const float* __restrict__ W, f16* __restrict__ Wt, int N)
{
    int lane = threadIdx.x;
    int k0 = blockIdx.x * 8;
    int n = blockIdx.y * 64 + lane;
    f16x8 o;
#pragma unroll
    for (int j = 0; j < 8; j++) o[j] = (f16)W[(size_t)(k0 + j) * N + n];
    *(f16x8*)(Wt + (size_t)n * CDIM + k0) = o;
}

// ---------------------------------------------------------------------------
// f16 MFMA GEMM mainloop: C[128x128] = A[128xK] B_t[128xK], K=1024
// ---------------------------------------------------------------------------
#define GEMM_MAINLOOP(Aimg, Bimg, M0, N0)                                         \
    __shared__ f16 As[128][32], Bs[128][32];                                      \
    const int tid = threadIdx.x, wave = tid >> 6, lane = tid & 63;                \
    const int l16 = lane & 15, quad = lane >> 4;                                  \
    const int wm = wave >> 1, wn = wave & 1;                                      \
    f32x4 acc[4][4];                                                              \
    _Pragma("unroll") for (int i = 0; i < 4; i++)                                 \
        _Pragma("unroll") for (int j = 0; j < 4; j++)                             \
            acc[i][j] = (f32x4){0.f, 0.f, 0.f, 0.f};                              \
    const f16* sbase = (wave < 2) ? (Aimg) : (Bimg);                              \
    f16* lbase = ((wave < 2) ? &As[0][0] : &Bs[0][0]) + (wave & 1) * 2048;        \
    const size_t srow0 = ((wave < 2) ? (size_t)(M0) : (size_t)(N0)) + (wave & 1) * 64; \
    const int srow = lane >> 2, schunk = (lane & 3) << 3;                         \
    for (int k0 = 0; k0 < CDIM; k0 += 32) {                                       \
        _Pragma("unroll") for (int it = 0; it < 4; it++)                          \
            gl_lds16(sbase + (srow0 + it * 16 + srow) * CDIM + k0 + schunk,       \
                     lbase + it * 512);                                           \
        __syncthreads();                                                          \
        f16x8 fa[4], fb[4];                                                       \
        _Pragma("unroll") for (int mi = 0; mi < 4; mi++)                          \
            fa[mi] = *(const f16x8*)&As[wm * 64 + mi * 16 + l16][quad * 8];       \
        _Pragma("unroll") for (int ni = 0; ni < 4; ni++)                          \
            fb[ni] = *(const f16x8*)&Bs[wn * 64 + ni * 16 + l16][quad * 8];       \
        _Pragma("unroll") for (int mi = 0; mi < 4; mi++)                          \
            _Pragma("unroll") for (int ni = 0; ni < 4; ni++)                      \
                acc[mi][ni] = __builtin_amdgcn_mfma_f32_16x16x32_f16(             \
                    fa[mi], fb[ni], acc[mi][ni], 0, 0, 0);                        \
        __syncthreads();                                                          \
    }

// ---------------------------------------------------------------------------
// QKV GEMM (f16 MFMA), fused bias + RoPE; writes q/k/v f16 in [bh][t][d].
// Q is pre-scaled by (1/8)*log2(e): attention then uses exp2 directly.
// ---------------------------------------------------------------------------
__global__ __launch_bounds__(256) void qkv_gemm_kernel(
    const f16* __restrict__ Xf, const f16* __restrict__ Wt,
    const float* __restrict__ bias,
    const float* __restrict__ ctab, const float* __restrict__ stab,
    f16* __restrict__ qf, f16* __restrict__ kf, f16* __restrict__ vf)
{
    const int m0 = blockIdx.x * 128;
    const int n0 = blockIdx.y * 128;
    GEMM_MAINLOOP(Xf, Wt, m0, n0)

    const int ncol0 = n0 + wn * 64;            // 64-aligned -> one head group
    const int w = ncol0 >> 10;                 // 0=q 1=k 2=v
    const int h = (ncol0 >> 6) & 15;
    const int b = m0 >> 11;
    const int trow0 = (m0 & 2047) + wm * 64 + quad * 4;
    float bia[4];
#pragma unroll
    for (int ni = 0; ni < 4; ni++) bia[ni] = bias[ncol0 + ni * 16 + l16];

    if (w < 2) {
        f16* oq = w ? kf : qf;
        const float sc = w ? 1.0f : 0.125f * 1.44269504088896f;  // fold softmax scale + log2e into Q
#pragma unroll
        for (int mi = 0; mi < 4; mi++) {
#pragma unroll
            for (int i = 0; i < 4; i++) {
                int t = trow0 + mi * 16 + i;
                size_t rowoff = ((size_t)(b * NH + h) * T_SEQ + t) * DHD;
#pragma unroll
                for (int np = 0; np < 2; np++) {
                    int d = np * 16 + l16;             // 0..31
                    float v0 = acc[mi][np][i] + bia[np];
                    float v1 = acc[mi][np + 2][i] + bia[np + 2];
                    float c = ctab[(t << 5) + d];
                    float s = stab[(t << 5) + d];
                    oq[rowoff + d]      = (f16)((v0 * c - v1 * s) * sc);
                    oq[rowoff + d + 32] = (f16)((v1 * c + v0 * s) * sc);
                }
            }
        }
    } else {
#pragma unroll
        for (int mi = 0; mi < 4; mi++) {
#pragma unroll
            for (int i = 0; i < 4; i++) {
                int t = trow0 + mi * 16 + i;
                size_t rowoff = ((size_t)(b * NH + h) * T_SEQ + t) * DHD;
#pragma unroll
                for (int ni = 0; ni < 4; ni++)
                    vf[rowoff + ni * 16 + l16] = (f16)(acc[mi][ni][i] + bia[ni]);
            }
        }
    }
}

// ---------------------------------------------------------------------------
// V transpose: vf [bh][t][d] f16 -> vt [bh][d][t] f16
// ---------------------------------------------------------------------------
__global__ __launch_bounds__(256) void vt_kernel(
    const f16* __restrict__ vf, f16* __restrict__ vt)
{
    __shared__ f16 Ls[64][72];
    const int tid = threadIdx.x;
    const int tb = blockIdx.x;   // 0..31
    const int bh = blockIdx.y;   // 0..63
#pragma unroll
    for (int p = 0; p < 2; p++) {
        int idx = tid + p * 256;
        int r = idx >> 3, c8 = (idx & 7) << 3;
        *(f16x8*)&Ls[r][c8] =
            *(const f16x8*)(vf + ((size_t)bh * T_SEQ + tb * 64 + r) * DHD + c8);
    }
    __syncthreads();
#pragma unroll
    for (int p = 0; p < 2; p++) {
        int idx = tid + p * 256;
        int d = idx >> 3, t8 = (idx & 7) << 3;
        f16x8 o;
#pragma unroll
        for (int j = 0; j < 8; j++) o[j] = Ls[t8 + j][d];
        *(f16x8*)(vt + ((size_t)bh * DHD + d) * T_SEQ + (size_t)tb * 64 + t8) = o;
    }
}

// ---------------------------------------------------------------------------
// f16 MFMA flash attention, v3: occupancy + L2 locality.
//  - 256-query blocks, 4 waves x 64 queries; grid 512 (1D), bid = qt*64+bh so
//    bid%8 = bh%8 -> all 8 q-blocks of a bh land on ONE XCD (K/V L2 reuse;
//    8 bh/XCD x 512KB = 4MB = L2)
//  - single-buffer K/V LDS [64][68] (pad 68: 2-way conflicts only) with
//    REGISTER prefetch issued a full tile ahead; 2 barriers/tile
//  - LDS 36KB -> 4 blocks/CU by LDS; launch_bounds(256,3) -> >=3 blocks/CU
//  - S^T trick (mfma A=K, B=Q) -> P packs as b64, reads as b128 A-frags
//  - no-max softmax via exp2 (Q pre-scaled by 0.125*log2e)
// ---------------------------------------------------------------------------
__global__ __launch_bounds__(256, 3) void attn_kernel(
    const f16* __restrict__ qf, const f16* __restrict__ kf,
    const f16* __restrict__ vt, f16* __restrict__ ab)
{
    __shared__ f16 Kb[64][68];       // [key][d]     8704 B
    __shared__ f16 Vb[64][68];       // [d][key]     8704 B
    __shared__ f16 Pb[4][64][36];    // per-wave [query][key%32]  18432 B
    __shared__ float Lb[4][64];      // per-wave 1/l  1024 B

    const int tid  = threadIdx.x;
    const int wave = tid >> 6, lane = tid & 63;
    const int l16  = lane & 15, quad = lane >> 4;
    const int bid = blockIdx.x;              // 0..511
    const int bh = bid & 63;                 // XCD = bid%8 = bh%8
    const int qt = bid >> 6;                 // 0..7
    const int q0 = qt * 256 + wave * 64;     // wave's query base

    const f16* kbase = kf + (size_t)bh * T_SEQ * DHD;
    const f16* vbase = vt + (size_t)bh * DHD * T_SEQ;

    // Q B-frags [qsub][ks]: B[n=query=l16][k=d=quad*8+j]
    f16x8 qfr[4][2];
#pragma unroll
    for (int qs = 0; qs < 4; qs++) {
        const f16* qrow = qf + ((size_t)bh * T_SEQ + q0 + qs * 16 + l16) * DHD;
        qfr[qs][0] = *(const f16x8*)(qrow + quad * 8);
        qfr[qs][1] = *(const f16x8*)(qrow + 32 + quad * 8);
    }

    f32x4 o[4][4];    // [qsub][dt]
#pragma unroll
    for (int qs = 0; qs < 4; qs++)
#pragma unroll
        for (int dt = 0; dt < 4; dt++) o[qs][dt] = (f32x4){0.f, 0.f, 0.f, 0.f};
    float lp[4] = {0.f, 0.f, 0.f, 0.f};

    // staging map: 256 threads x 2 rounds x b128 per array
    const int srow = tid >> 3;          // 0..31
    const int scol = (tid & 7) << 3;    // 0..56

    f16x8 kreg[2], vreg[2];
#define PREFETCH(KT)                                                              \
    _Pragma("unroll") for (int r = 0; r < 2; r++) {                               \
        kreg[r] = *(const f16x8*)(kbase + (size_t)((KT) * 64 + srow + r * 32) * DHD + scol); \
        vreg[r] = *(const f16x8*)(vbase + (size_t)(srow + r * 32) * T_SEQ + (KT) * 64 + scol); \
    }
#define COMMIT()                                                                  \
    _Pragma("unroll") for (int r = 0; r < 2; r++) {                               \
        *(f16x8*)&Kb[srow + r * 32][scol] = kreg[r];                              \
        *(f16x8*)&Vb[srow + r * 32][scol] = vreg[r];                              \
    }

    PREFETCH(0)
    COMMIT()
    __syncthreads();

    for (int kt = 0; kt < 32; kt++) {
        if (kt < 31) { PREFETCH(kt + 1) }   // lands during this tile's compute

#pragma unroll
        for (int half = 0; half < 2; half++) {
            // ---- S^T for 32 keys x 64 queries ----
            f32x4 sc[2][4];   // [keysub][qsub]
#pragma unroll
            for (int k2 = 0; k2 < 2; k2++)
#pragma unroll
                for (int qs = 0; qs < 4; qs++) sc[k2][qs] = (f32x4){0.f, 0.f, 0.f, 0.f};
#pragma unroll
            for (int k2 = 0; k2 < 2; k2++) {
                const int keyt = half * 2 + k2;
#pragma unroll
                for (int ks = 0; ks < 2; ks++) {
                    f16x8 kfr = *(const f16x8*)&Kb[keyt * 16 + l16][ks * 32 + quad * 8];
#pragma unroll
                    for (int qs = 0; qs < 4; qs++)
                        sc[k2][qs] = __builtin_amdgcn_mfma_f32_16x16x32_f16(
                            kfr, qfr[qs][ks], sc[k2][qs], 0, 0, 0);
                }
            }
            // ---- exp2, l accumulate, pack P (b64 writes) ----
#pragma unroll
            for (int k2 = 0; k2 < 2; k2++) {
#pragma unroll
                for (int qs = 0; qs < 4; qs++) {
                    float p0 = exp2f(sc[k2][qs][0]);
                    float p1 = exp2f(sc[k2][qs][1]);
                    float p2 = exp2f(sc[k2][qs][2]);
                    float p3 = exp2f(sc[k2][qs][3]);
                    lp[qs] += (p0 + p1) + (p2 + p3);
                    f16x4 pv;
                    pv[0] = (f16)p0; pv[1] = (f16)p1;
                    pv[2] = (f16)p2; pv[3] = (f16)p3;
                    *(f16x4*)&Pb[wave][qs * 16 + l16][k2 * 16 + quad * 4] = pv;
                }
            }
            // ---- PV for this 32-key chunk ----
            f16x8 pfr[4];
#pragma unroll
            for (int qs = 0; qs < 4; qs++)
                pfr[qs] = *(const f16x8*)&Pb[wave][qs * 16 + l16][quad * 8];
#pragma unroll
            for (int dt = 0; dt < 4; dt++) {
                f16x8 vfr = *(const f16x8*)&Vb[dt * 16 + l16][half * 32 + quad * 8];
#pragma unroll
                for (int qs = 0; qs < 4; qs++)
                    o[qs][dt] = __builtin_amdgcn_mfma_f32_16x16x32_f16(
                        pfr[qs], vfr, o[qs][dt], 0, 0, 0);
            }
        }

        __syncthreads();                 // all reads of Kb/Vb done
        if (kt < 31) { COMMIT() }        // write prefetched tile
        __syncthreads();                 // writes visible
    }
#undef PREFETCH
#undef COMMIT

    // ---- l reduction (lanes l16,l16+16,.. hold partials for same query) ----
#pragma unroll
    for (int qs = 0; qs < 4; qs++) {
        float l = lp[qs];
        l += __shfl_xor(l, 16);
        l += __shfl_xor(l, 32);
        Lb[wave][qs * 16 + l16] = 1.f / l;
    }

    // ---- epilogue: normalize, write ab[q][h*64+d] ----
    const int b = bh >> 4, h = bh & 15;
#pragma unroll
    for (int qs = 0; qs < 4; qs++) {
        f32x4 iv = *(const f32x4*)&Lb[wave][qs * 16 + quad * 4];
#pragma unroll
        for (int i = 0; i < 4; i++) {
            int m = b * T_SEQ + qt * 256 + wave * 64 + qs * 16 + quad * 4 + i;
#pragma unroll
            for (int dt = 0; dt < 4; dt++)
                ab[(size_t)m * CDIM + h * 64 + dt * 16 + l16] = (f16)(o[qs][dt][i] * iv[i]);
        }
    }
}

// ---------------------------------------------------------------------------
// Output GEMM (f16 MFMA): out = ab @ Wout + bias (fp32 out)
// ---------------------------------------------------------------------------
__global__ __launch_bounds__(256) void out_gemm_kernel(
    const f16* __restrict__ Ab, const f16* __restrict__ Wt,
    const float* __restrict__ bias, float* __restrict__ out)
{
    const int m0 = blockIdx.x * 128;
    const int n0 = blockIdx.y * 128;
    GEMM_MAINLOOP(Ab, Wt, m0, n0)

    const int ncol0 = n0 + wn * 64;
    float bia[4];
#pragma unroll
    for (int ni = 0; ni < 4; ni++) bia[ni] = bias[ncol0 + ni * 16 + l16];
#pragma unroll
    for (int mi = 0; mi < 4; mi++) {
#pragma unroll
        for (int i = 0; i < 4; i++) {
            int m = m0 + wm * 64 + mi * 16 + quad * 4 + i;
#pragma unroll
            for (int ni = 0; ni < 4; ni++)
                out[(size_t)m * CDIM + ncol0 + ni * 16 + l16] = acc[mi][ni][i] + bia[ni];
        }
    }
}

// ---------------------------------------------------------------------------
extern "C" void kernel_launch(void* const* d_in, const int* in_sizes, int n_in,
                              void* d_out, int out_size, void* d_ws, size_t ws_size,
                              hipStream_t stream)
{
    const float* x    = (const float*)d_in[0];
    const float* Wqkv = (const float*)d_in[1];
    const float* bqkv = (const float*)d_in[2];
    const float* Wout = (const float*)d_in[3];
    const float* bout = (const float*)d_in[4];
    float* out = (float*)d_out;

    const size_t XSZ  = (size_t)MROWS * CDIM;        // 8,388,608
    const size_t WQSZ = (size_t)3072 * CDIM;         // 3,145,728
    const size_t WOSZ = (size_t)CDIM * CDIM;         // 1,048,576
    const size_t QSZ  = (size_t)BHN * T_SEQ * DHD;   // 8,388,608

    char* p = (char*)d_ws;
    f16* Xf  = (f16*)p; p += XSZ * 2;
    f16* Wqt = (f16*)p; p += WQSZ * 2;
    f16* Wot = (f16*)p; p += WOSZ * 2;
    f16* qf  = (f16*)p; p += QSZ * 2;
    f16* kf  = (f16*)p; p += QSZ * 2;
    f16* vf  = (f16*)p; p += QSZ * 2;
    f16* vtb = (f16*)p; p += QSZ * 2;
    f16* ab  = (f16*)p; p += QSZ * 2;
    float* ctab = (float*)p; p += T_SEQ * 32 * 4;
    float* stab = (float*)p; p += T_SEQ * 32 * 4;
    // total ~110 MB

    rope_tables_kernel<<<256, 256, 0, stream>>>(ctab, stab);
    xcvt_kernel<<<(int)(XSZ / 8 / 256), 256, 0, stream>>>(x, Xf);
    wcvt_kernel<<<dim3(128, 48), 64, 0, stream>>>(Wqkv, Wqt, 3072);
    wcvt_kernel<<<dim3(128, 16), 64, 0, stream>>>(Wout, Wot, 1024);
    qkv_gemm_kernel<<<dim3(64, 24), 256, 0, stream>>>(
        Xf, Wqt, bqkv, ctab, stab, qf, kf, vf);
    vt_kernel<<<dim3(32, BHN), 256, 0, stream>>>(vf, vtb);
    attn_kernel<<<512, 256, 0, stream>>>(qf, kf, vtb, ab);
    out_gemm_kernel<<<dim3(64, 8), 256, 0, stream>>>(ab, Wot, bout, out);
}